// Round 1
// baseline (156.839 us; speedup 1.0000x reference)
//
#include <hip/hip_runtime.h>

#define NC 19
#define HW_ (512 * 1024)
#define NPIX (2 * HW_)
#define THRESH 0.9f
#define IGNORE_L 255

// Main pass: softmax over C=19 (strided class planes), weight + renorm,
// write wp, per-pixel confident-class histogram + squared-error partial.
__global__ __launch_bounds__(256) void calib_main(
    const float* __restrict__ pred,
    const float* __restrict__ weight,
    const int*   __restrict__ label,
    float* __restrict__ wp_out,   // == d_out + 1  (4B-aligned only!)
    int*   __restrict__ g_hist,
    float* __restrict__ g_se)
{
    __shared__ int   hist[NC];
    __shared__ float wsum[4];

    const int tid = threadIdx.x;
    if (tid < NC) hist[tid] = 0;
    __syncthreads();

    const int gid = blockIdx.x * 256 + tid;        // one work item = 4 pixels
    const int b   = gid / (HW_ / 4);               // batch 0/1
    const int hw  = (gid - b * (HW_ / 4)) * 4;     // pixel offset within plane

    const float* p0 = pred + (size_t)b * NC * HW_ + hw;

    // Load 19 class values for 4 consecutive pixels (16B-aligned float4).
    float x[NC][4];
#pragma unroll
    for (int c = 0; c < NC; ++c) {
        float4 v = *reinterpret_cast<const float4*>(p0 + (size_t)c * HW_);
        x[c][0] = v.x; x[c][1] = v.y; x[c][2] = v.z; x[c][3] = v.w;
    }

    float wc[NC];
#pragma unroll
    for (int c = 0; c < NC; ++c) wc[c] = weight[c];   // uniform addr -> s_load

    float mx[4] = { x[0][0], x[0][1], x[0][2], x[0][3] };
#pragma unroll
    for (int c = 1; c < NC; ++c)
#pragma unroll
        for (int j = 0; j < 4; ++j) mx[j] = fmaxf(mx[j], x[c][j]);

    float den[4] = {0.f, 0.f, 0.f, 0.f};
#pragma unroll
    for (int c = 0; c < NC; ++c)
#pragma unroll
        for (int j = 0; j < 4; ++j) {
            float e = wc[c] * __expf(x[c][j] - mx[j]);
            x[c][j] = e;
            den[j] += e;
        }

    float rden[4];
#pragma unroll
    for (int j = 0; j < 4; ++j) rden[j] = 1.0f / den[j];

    int4 lblv = *reinterpret_cast<const int4*>(label + (size_t)b * HW_ + hw);
    int lbls[4] = { lblv.x, lblv.y, lblv.z, lblv.w };

    float sumsq[4] = {0.f, 0.f, 0.f, 0.f};
    float wl[4]    = {0.f, 0.f, 0.f, 0.f};
    int   cls[4]   = {-1, -1, -1, -1};

    float* o0 = wp_out + (size_t)b * NC * HW_ + hw;
#pragma unroll
    for (int c = 0; c < NC; ++c) {
#pragma unroll
        for (int j = 0; j < 4; ++j) {
            float wp = x[c][j] * rden[j];
            o0[(size_t)c * HW_ + j] = wp;          // scalar stores (dest is 4B-aligned)
            sumsq[j] += wp * wp;
            if (wp > THRESH)   cls[j] = c;          // at most one class can qualify
            if (lbls[j] == c)  wl[j]  = wp;
        }
    }

    float se = 0.f;
#pragma unroll
    for (int j = 0; j < 4; ++j) {
        float s;
        if (lbls[j] >= 0 && lbls[j] < NC) s = sumsq[j] - 2.f * wl[j] + 1.f;
        else                              s = sumsq[j];   // out-of-range -> all-zero one-hot
        if (lbls[j] == IGNORE_L)          s = 0.f;        // ignored pixels zeroed
        se += s;
        if (cls[j] >= 0) atomicAdd(&hist[cls[j]], 1);
    }

    // wave (64-lane) shuffle reduce, then cross-wave via LDS
#pragma unroll
    for (int off = 32; off > 0; off >>= 1) se += __shfl_down(se, off, 64);
    if ((tid & 63) == 0) wsum[tid >> 6] = se;
    __syncthreads();

    if (tid == 0) atomicAdd(g_se, wsum[0] + wsum[1] + wsum[2] + wsum[3]);
    if (tid < NC) atomicAdd(&g_hist[tid], hist[tid]);
}

__global__ void calib_final(const int* __restrict__ g_hist,
                            const float* __restrict__ g_se,
                            float* __restrict__ out)
{
    if (threadIdx.x == 0 && blockIdx.x == 0) {
        const float prior[NC] = {32.07f, 5.71f, 20.7f, 0.564f, 0.761f, 1.054f,
                                 0.1696f, 0.5014f, 13.4993f, 0.8981f, 3.6445f,
                                 1.1458f, 0.1393f, 6.0f, 0.2949f, 0.1954f,
                                 0.2341f, 0.0818f, 0.3917f};
        float psum = 0.f, total = 0.f;
        for (int i = 0; i < NC; ++i) { psum += prior[i]; total += (float)g_hist[i]; }
        float rl = 0.f;
        for (int i = 0; i < NC; ++i) {
            float d = (float)g_hist[i] / total - prior[i] / psum;
            rl += d * d;
        }
        float mse = g_se[0] * (1.0f / (float)NPIX);
        out[0] = rl + 0.05f * mse;
    }
}

extern "C" void kernel_launch(void* const* d_in, const int* in_sizes, int n_in,
                              void* d_out, int out_size, void* d_ws, size_t ws_size,
                              hipStream_t stream) {
    const float* pred   = (const float*)d_in[0];
    const float* weight = (const float*)d_in[1];
    const int*   label  = (const int*)d_in[2];
    float* out    = (float*)d_out;
    int*   g_hist = (int*)d_ws;
    float* g_se   = (float*)((char*)d_ws + 256);

    // d_ws is re-poisoned to 0xAA before every launch -> zero our accumulators.
    hipMemsetAsync(d_ws, 0, 512, stream);

    const int nwork = NPIX / 4;                 // 262144 work items
    calib_main<<<nwork / 256, 256, 0, stream>>>(pred, weight, label,
                                                out + 1, g_hist, g_se);
    calib_final<<<1, 64, 0, stream>>>(g_hist, g_se, out);
}